// Round 6
// baseline (206.075 us; speedup 1.0000x reference)
//
#include <hip/hip_runtime.h>

// DotAttentionLayer: q,k,v are [B,N] (B=16, N=4096). Head dim == 1, so
//   dist[b,i,j] = softmax_j(q[b,i]*k[b,j]/64); out[b,i] = sum_j dist*v[b,j]
// d_out = [ output (B*N f32) | distribution (B*N*N f32) ] ~1.07 GB writes ->
// write-BW-bound. Fill-kernel floor ~163 us @ 6.6 TB/s.
//
// R6: persistent blocks. Each 256-thread block owns 32 consecutive rows of
// one batch; k/v tiles live in registers across rows (prologue paid once per
// 32 rows instead of per row), per-row reduce uses double-buffered LDS
// partials (ONE barrier/row), stores are plain (nt regressed, R5 A/B).

typedef float f32x4 __attribute__((ext_vector_type(4)));

constexpr int kThreads = 256;
constexpr int kRows = 32;                       // rows per block
constexpr float kInvSqrtScale = 1.0f / 64.0f;   // 1/sqrt(4096)

__device__ __forceinline__ float wave_reduce_sum(float x) {
#pragma unroll
  for (int off = 32; off > 0; off >>= 1) x += __shfl_down(x, off, 64);
  return x;
}

__global__ __launch_bounds__(kThreads) void dot_attn_rows_kernel(
    const float* __restrict__ q, const float* __restrict__ k,
    const float* __restrict__ v, float* __restrict__ out,
    float* __restrict__ dist, int N) {
  const int chunksPerBatch = N / kRows;           // 128
  const int b = blockIdx.x / chunksPerBatch;
  const int i0 = (blockIdx.x % chunksPerBatch) * kRows;
  const int row0 = b * N + i0;

  const int nf4 = N / 4;  // 1024 float4 per row
  const f32x4* kb = reinterpret_cast<const f32x4*>(k) + (size_t)b * nf4;
  const f32x4* vb = reinterpret_cast<const f32x4*>(v) + (size_t)b * nf4;

  // k/v register-resident for all 32 rows (coalesced t*256+tid layout).
  f32x4 kr[4], vr[4];
#pragma unroll
  for (int t = 0; t < 4; ++t) {
    const int idx = t * kThreads + threadIdx.x;
    kr[t] = kb[idx];
    vr[t] = vb[idx];
  }

  __shared__ float red_s[2][4];   // double-buffered per-wave partials
  __shared__ float red_pv[2][4];
  const int lane = threadIdx.x & 63;
  const int wid = threadIdx.x >> 6;

  for (int r = 0; r < kRows; ++r) {
    const float a = q[row0 + r] * kInvSqrtScale;  // wave-uniform scalar load

    f32x4 e[4];
    float s = 0.f, pv = 0.f;
#pragma unroll
    for (int t = 0; t < 4; ++t) {
      f32x4 ee;
      ee.x = __expf(a * kr[t].x);
      ee.y = __expf(a * kr[t].y);
      ee.z = __expf(a * kr[t].z);
      ee.w = __expf(a * kr[t].w);
      e[t] = ee;
      s  += (ee.x + ee.y) + (ee.z + ee.w);
      pv += (ee.x * vr[t].x + ee.y * vr[t].y) +
            (ee.z * vr[t].z + ee.w * vr[t].w);
    }

    s = wave_reduce_sum(s);
    pv = wave_reduce_sum(pv);
    const int pb = r & 1;
    if (lane == 0) { red_s[pb][wid] = s; red_pv[pb][wid] = pv; }
    __syncthreads();  // one barrier/row; [2] buffers kill the WAR hazard
    const float stot = (red_s[pb][0] + red_s[pb][1]) +
                       (red_s[pb][2] + red_s[pb][3]);
    const float rinv = 1.0f / stot;

    f32x4* drow = reinterpret_cast<f32x4*>(dist) + (size_t)(row0 + r) * nf4;
#pragma unroll
    for (int t = 0; t < 4; ++t) {
      drow[t * kThreads + threadIdx.x] = e[t] * rinv;  // full-line wave stores
    }

    if (threadIdx.x == 0) {
      const float pvtot = (red_pv[pb][0] + red_pv[pb][1]) +
                          (red_pv[pb][2] + red_pv[pb][3]);
      out[row0 + r] = pvtot * rinv;
    }
  }
}

extern "C" void kernel_launch(void* const* d_in, const int* in_sizes, int n_in,
                              void* d_out, int out_size, void* d_ws, size_t ws_size,
                              hipStream_t stream) {
  // setup_inputs dict order: query, value, key  (f32 each, [B,N])
  const float* q = (const float*)d_in[0];
  const float* v = (const float*)d_in[1];
  const float* k = (const float*)d_in[2];

  const int S = in_sizes[0];                      // B*N = 65536 rows
  const int N = (int)((size_t)out_size / S) - 1;  // 4096
  float* out = (float*)d_out;                     // [B*N]
  float* dist = out + S;                          // [B*N*N]

  const int grid = S / kRows;                     // 2048 blocks = 8/CU
  dot_attn_rows_kernel<<<grid, kThreads, 0, stream>>>(q, k, v, out, dist, N);
}

// Round 7
// 199.753 us; speedup vs baseline: 1.0317x; 1.0317x over previous
//
#include <hip/hip_runtime.h>

// DotAttentionLayer: q,k,v are [B,N] (B=16, N=4096). Head dim == 1, so
//   dist[b,i,j] = softmax_j(q[b,i]*k[b,j]/64); out[b,i] = sum_j dist*v[b,j]
// d_out = [ output (B*N f32) | distribution (B*N*N f32) ] ~1.07 GB writes ->
// write-BW-bound. Fill-kernel floor ~163 us @ 6.6 TB/s; R5 (1 row/block) hit
// 177.7 us (6.07 TB/s).
//
// R7: software-pipelined rows. 8 rows per block; row r-1's stores issue
// BETWEEN the LDS partial-write and the __syncthreads of row r, so the
// barrier wait is spent issuing stores instead of stalling (R6 showed that
// serial per-row barriers with phase-locked blocks cause store droughts).
// k/v register-resident (loaded once per 8 rows); e[] double-buffered with
// static indexing only (full unroll). Plain stores (nt regressed, R5 A/B).

typedef float f32x4 __attribute__((ext_vector_type(4)));

constexpr int kThreads = 256;
constexpr int kRows = 8;                        // rows per block, pipelined
constexpr float kInvSqrtScale = 1.0f / 64.0f;   // 1/sqrt(4096)

__device__ __forceinline__ float wave_reduce_sum(float x) {
#pragma unroll
  for (int off = 32; off > 0; off >>= 1) x += __shfl_down(x, off, 64);
  return x;
}

__global__ __launch_bounds__(kThreads) void dot_attn_pipe_kernel(
    const float* __restrict__ q, const float* __restrict__ k,
    const float* __restrict__ v, float* __restrict__ out,
    float* __restrict__ dist, int N) {
  const int chunksPerBatch = N / kRows;           // 512
  const int b = blockIdx.x / chunksPerBatch;
  const int i0 = (blockIdx.x % chunksPerBatch) * kRows;
  const int row0 = b * N + i0;
  const int nf4 = N / 4;                          // 1024 float4 per row

  const f32x4* kb = reinterpret_cast<const f32x4*>(k) + (size_t)b * nf4;
  const f32x4* vb = reinterpret_cast<const f32x4*>(v) + (size_t)b * nf4;

  // k/v register-resident for all 8 rows (coalesced t*256+tid layout).
  f32x4 kr[4], vr[4];
#pragma unroll
  for (int t = 0; t < 4; ++t) {
    const int idx = t * kThreads + threadIdx.x;
    kr[t] = kb[idx];
    vr[t] = vb[idx];
  }

  __shared__ float red_s[2][4];   // double-buffered per-wave partials
  __shared__ float red_pv[2][4];
  const int lane = threadIdx.x & 63;
  const int wid = threadIdx.x >> 6;

  f32x4 e[2][4];                  // [r&1][t], all indices compile-time
  float rinv_prev = 0.f;

#pragma unroll
  for (int r = 0; r < kRows; ++r) {
    const float a = q[row0 + r] * kInvSqrtScale;  // block-uniform (s_load)

    float s = 0.f, pv = 0.f;
#pragma unroll
    for (int t = 0; t < 4; ++t) {
      f32x4 ee;
      ee.x = __expf(a * kr[t].x);
      ee.y = __expf(a * kr[t].y);
      ee.z = __expf(a * kr[t].z);
      ee.w = __expf(a * kr[t].w);
      e[r & 1][t] = ee;
      s  += (ee.x + ee.y) + (ee.z + ee.w);
      pv += (ee.x * vr[t].x + ee.y * vr[t].y) +
            (ee.z * vr[t].z + ee.w * vr[t].w);
    }

    s = wave_reduce_sum(s);
    pv = wave_reduce_sum(pv);
    if (lane == 0) { red_s[r & 1][wid] = s; red_pv[r & 1][wid] = pv; }

    if (r > 0) {
      // Store row r-1 while waves converge on the barrier: the barrier wait
      // becomes store-issue time instead of a stall.
      f32x4* drow =
          reinterpret_cast<f32x4*>(dist) + (size_t)(row0 + r - 1) * nf4;
#pragma unroll
      for (int t = 0; t < 4; ++t)
        drow[t * kThreads + threadIdx.x] = e[(r - 1) & 1][t] * rinv_prev;
    }

    __syncthreads();  // [2] LDS buffers: next write to this slot is r+2,
                      // which every thread reaches only after this barrier.
    const float stot = (red_s[r & 1][0] + red_s[r & 1][1]) +
                       (red_s[r & 1][2] + red_s[r & 1][3]);
    rinv_prev = 1.0f / stot;

    if (threadIdx.x == 0) {
      const float pvtot = (red_pv[r & 1][0] + red_pv[r & 1][1]) +
                          (red_pv[r & 1][2] + red_pv[r & 1][3]);
      out[row0 + r] = pvtot * rinv_prev;
    }
  }

  // Epilogue: last row's stores.
  f32x4* drow =
      reinterpret_cast<f32x4*>(dist) + (size_t)(row0 + kRows - 1) * nf4;
#pragma unroll
  for (int t = 0; t < 4; ++t)
    drow[t * kThreads + threadIdx.x] = e[(kRows - 1) & 1][t] * rinv_prev;
}

extern "C" void kernel_launch(void* const* d_in, const int* in_sizes, int n_in,
                              void* d_out, int out_size, void* d_ws, size_t ws_size,
                              hipStream_t stream) {
  // setup_inputs dict order: query, value, key  (f32 each, [B,N])
  const float* q = (const float*)d_in[0];
  const float* v = (const float*)d_in[1];
  const float* k = (const float*)d_in[2];

  const int S = in_sizes[0];                      // B*N = 65536 rows
  const int N = (int)((size_t)out_size / S) - 1;  // 4096
  float* out = (float*)d_out;                     // [B*N]
  float* dist = out + S;                          // [B*N*N]

  const int grid = S / kRows;                     // 8192 blocks
  dot_attn_pipe_kernel<<<grid, kThreads, 0, stream>>>(q, k, v, out, dist, N);
}

// Round 8
// 182.320 us; speedup vs baseline: 1.1303x; 1.0956x over previous
//
#include <hip/hip_runtime.h>

// DotAttentionLayer: q,k,v are [B,N] (B=16, N=4096). Head dim == 1, so
//   dist[b,i,j] = softmax_j(q[b,i]*k[b,j]/64); out[b,i] = sum_j dist*v[b,j]
// d_out = [ output (B*N f32) | distribution (B*N*N f32) ] ~1.07 GB writes ->
// write-BW-bound. History: R5 (1 row/256-thr block, plain stores) = 177.7 us
// (6.07 TB/s). R4 wave-per-row (e[16] -> ~90 VGPR) = 195. R6/R7 multi-row
// blocks (lockstep / pipelined barriers) = 206/200. Fill kernel = 6.5-6.7
// TB/s. Conclusion so far: many small desynchronized blocks win.
//
// R8: R5 structure with 128-thread (2-wave) blocks. Barrier couples 2 waves
// instead of 4 (tighter convergence), 16 independent blocks/CU instead of 8
// (finer store-stream interleave). e[8] = 32 VGPR keeps total <= 64 VGPR so
// occupancy stays at 8 waves/SIMD.

typedef float f32x4 __attribute__((ext_vector_type(4)));

constexpr int kThreads = 128;                   // 2 waves per block
constexpr int kF4PerThread = 8;                 // 1024 f32x4 per row / 128
constexpr float kInvSqrtScale = 1.0f / 64.0f;   // 1/sqrt(4096)

__device__ __forceinline__ float wave_reduce_sum(float x) {
#pragma unroll
  for (int off = 32; off > 0; off >>= 1) x += __shfl_down(x, off, 64);
  return x;
}

__global__ __launch_bounds__(kThreads) void dot_attn_row_kernel(
    const float* __restrict__ q, const float* __restrict__ k,
    const float* __restrict__ v, float* __restrict__ out,
    float* __restrict__ dist, int N) {
  const int row = blockIdx.x;        // row = b*N + i
  const int b = row / N;
  const float a = q[row] * kInvSqrtScale;

  const f32x4* kb = reinterpret_cast<const f32x4*>(k) + (size_t)b * (N / 4);
  const f32x4* vb = reinterpret_cast<const f32x4*>(v) + (size_t)b * (N / 4);

  // 8 f32x4 per thread at stride 128 (each wave inst = contiguous 1 KB).
  f32x4 e[kF4PerThread];
  float s = 0.f, pv = 0.f;
#pragma unroll
  for (int t = 0; t < kF4PerThread; ++t) {
    const int idx = t * kThreads + threadIdx.x;  // float4 index within row
    const f32x4 kk = kb[idx];
    const f32x4 vv = vb[idx];
    f32x4 ee;
    ee.x = __expf(a * kk.x);
    ee.y = __expf(a * kk.y);
    ee.z = __expf(a * kk.z);
    ee.w = __expf(a * kk.w);
    e[t] = ee;
    s  += (ee.x + ee.y) + (ee.z + ee.w);
    pv += (ee.x * vv.x + ee.y * vv.y) + (ee.z * vv.z + ee.w * vv.w);
  }

  // Block reduction: per-wave shuffle, then 2 partials through LDS.
  s = wave_reduce_sum(s);
  pv = wave_reduce_sum(pv);
  __shared__ float red_s[2];
  __shared__ float red_pv[2];
  const int lane = threadIdx.x & 63;
  const int wid = threadIdx.x >> 6;
  if (lane == 0) { red_s[wid] = s; red_pv[wid] = pv; }
  __syncthreads();
  const float stot = red_s[0] + red_s[1];
  const float rinv = 1.0f / stot;

  f32x4* drow = reinterpret_cast<f32x4*>(dist) + (size_t)row * (N / 4);
#pragma unroll
  for (int t = 0; t < kF4PerThread; ++t) {
    const int idx = t * kThreads + threadIdx.x;
    drow[idx] = e[t] * rinv;  // plain full-line wave stores (nt regressed)
  }

  if (threadIdx.x == 0) {
    out[row] = (red_pv[0] + red_pv[1]) * rinv;
  }
}

extern "C" void kernel_launch(void* const* d_in, const int* in_sizes, int n_in,
                              void* d_out, int out_size, void* d_ws, size_t ws_size,
                              hipStream_t stream) {
  // setup_inputs dict order: query, value, key  (f32 each, [B,N])
  const float* q = (const float*)d_in[0];
  const float* v = (const float*)d_in[1];
  const float* k = (const float*)d_in[2];

  const int S = in_sizes[0];                      // B*N = 65536 rows
  const int N = (int)((size_t)out_size / S) - 1;  // 4096
  float* out = (float*)d_out;                     // [B*N]
  float* dist = out + S;                          // [B*N*N]

  dot_attn_row_kernel<<<S, kThreads, 0, stream>>>(q, k, v, out, dist, N);
}

// Round 9
// 176.340 us; speedup vs baseline: 1.1686x; 1.0339x over previous
//
#include <hip/hip_runtime.h>

// DotAttentionLayer: q,k,v are [B,N] (B=16, N=4096). Head dim == 1, so
//   dist[b,i,j] = softmax_j(q[b,i]*k[b,j]/64); out[b,i] = sum_j dist*v[b,j]
// d_out = [ output (B*N f32) | distribution (B*N*N f32) ] ~1.07 GB writes ->
// write-BW-bound. Ladder: R2 tid*4+t layout = 823 us (2x write amp);
// R3 coalesced = 188.5; R5 plain stores (nt removed) = 177.7 (6.07 TB/s,
// 96.5% of float4-copy ceiling 6.29 TB/s). All structural variants lost:
// wave/row=195, 32-row block=206, 8-row pipeline=200, 2-wave block=182.
// -> R5's 1-row/4-wave-block shape is the local optimum; block-level TLP
// (8 blocks/CU) already hides the reduce+barrier latency.
//
// R9: exact R5 revert + compile-time N=4096 (b = row>>12 instead of a
// per-thread integer division by runtime N; ~1%).

typedef float f32x4 __attribute__((ext_vector_type(4)));

constexpr int kThreads = 256;
constexpr int kN = 4096;                       // fixed by harness shape
constexpr int kNF4 = kN / 4;                   // 1024 float4 per row
constexpr int kLogN = 12;                      // log2(kN)
constexpr float kInvSqrtScale = 1.0f / 64.0f;  // 1/sqrt(4096)

__device__ __forceinline__ float wave_reduce_sum(float x) {
#pragma unroll
  for (int off = 32; off > 0; off >>= 1) x += __shfl_down(x, off, 64);
  return x;
}

__global__ __launch_bounds__(kThreads) void dot_attn_row_kernel(
    const float* __restrict__ q, const float* __restrict__ k,
    const float* __restrict__ v, float* __restrict__ out,
    float* __restrict__ dist) {
  const int row = blockIdx.x;        // row = b*N + i
  const int b = row >> kLogN;        // N compile-time: shift, no division
  const float a = q[row] * kInvSqrtScale;

  const f32x4* kb = reinterpret_cast<const f32x4*>(k) + (size_t)b * kNF4;
  const f32x4* vb = reinterpret_cast<const f32x4*>(v) + (size_t)b * kNF4;

  // 1024 float4 per row; 4 per thread at stride 256 (coalesced full lines).
  f32x4 e[4];
  float s = 0.f, pv = 0.f;
#pragma unroll
  for (int t = 0; t < 4; ++t) {
    const int idx = t * kThreads + threadIdx.x;  // float4 index within row
    const f32x4 kk = kb[idx];
    const f32x4 vv = vb[idx];
    f32x4 ee;
    ee.x = __expf(a * kk.x);
    ee.y = __expf(a * kk.y);
    ee.z = __expf(a * kk.z);
    ee.w = __expf(a * kk.w);
    e[t] = ee;
    s  += (ee.x + ee.y) + (ee.z + ee.w);
    pv += (ee.x * vv.x + ee.y * vv.y) + (ee.z * vv.z + ee.w * vv.w);
  }

  // Block reduction: per-wave shuffle, then 4 partials through LDS.
  s = wave_reduce_sum(s);
  pv = wave_reduce_sum(pv);
  __shared__ float red_s[4];
  __shared__ float red_pv[4];
  const int lane = threadIdx.x & 63;
  const int wid = threadIdx.x >> 6;
  if (lane == 0) { red_s[wid] = s; red_pv[wid] = pv; }
  __syncthreads();
  const float stot = (red_s[0] + red_s[1]) + (red_s[2] + red_s[3]);
  const float rinv = 1.0f / stot;

  f32x4* drow = reinterpret_cast<f32x4*>(dist) + (size_t)row * kNF4;
#pragma unroll
  for (int t = 0; t < 4; ++t) {
    const int idx = t * kThreads + threadIdx.x;
    drow[idx] = e[t] * rinv;  // plain full-line wave stores (nt regressed, R5)
  }

  if (threadIdx.x == 0) {
    const float pvtot = (red_pv[0] + red_pv[1]) + (red_pv[2] + red_pv[3]);
    out[row] = pvtot * rinv;
  }
}

extern "C" void kernel_launch(void* const* d_in, const int* in_sizes, int n_in,
                              void* d_out, int out_size, void* d_ws, size_t ws_size,
                              hipStream_t stream) {
  // setup_inputs dict order: query, value, key  (f32 each, [B,N])
  const float* q = (const float*)d_in[0];
  const float* v = (const float*)d_in[1];
  const float* k = (const float*)d_in[2];

  const int S = in_sizes[0];                      // B*N = 65536 rows
  float* out = (float*)d_out;                     // [B*N]
  float* dist = out + S;                          // [B*N*N]

  dot_attn_row_kernel<<<S, kThreads, 0, stream>>>(q, k, v, out, dist);
}